// Round 14
// baseline (260.186 us; speedup 1.0000x reference)
//
#include <hip/hip_runtime.h>
#include <hip/hip_bf16.h>
#include <stdint.h>

typedef __bf16 bf16_t;
typedef bf16_t bf16x2 __attribute__((ext_vector_type(2)));
typedef bf16_t bf16x8 __attribute__((ext_vector_type(8)));
typedef float  f32x4  __attribute__((ext_vector_type(4)));
typedef float  f32x16 __attribute__((ext_vector_type(16)));
typedef unsigned uint2v __attribute__((ext_vector_type(2)));

#define NB_HEAD 16
#define DH      64
#define EMB     1024
#define BATCH   4
#define SEQ     2048
#define NTOK    (BATCH*SEQ)   // 8192

// scale * log2(e): folded into Q at projection time
#define QSCALE 0.1803368801111204f

// ---------------------------------------------------------------------------
// helpers
// ---------------------------------------------------------------------------
__device__ __forceinline__ void gload_lds16(const void* g, void* l) {
  __builtin_amdgcn_global_load_lds(
      (const __attribute__((address_space(1))) void*)g,
      (__attribute__((address_space(3))) void*)l, 16, 0, 0);
}

__device__ __forceinline__ uint32_t pkbf(float a, float b) {
  bf16x2 v = { (bf16_t)a, (bf16_t)b };     // fusable to v_cvt_pk_bf16_f32
  return __builtin_bit_cast(uint32_t, v);
}

__device__ __forceinline__ void cvt8_body(const float* __restrict__ in,
                                          bf16_t* __restrict__ out, int i) {
  const float4* p = reinterpret_cast<const float4*>(in) + (size_t)i * 2;
  float4 a = p[0], b = p[1];
  uint4 r;
  r.x = pkbf(a.x, a.y); r.y = pkbf(a.z, a.w);
  r.z = pkbf(b.x, b.y); r.w = pkbf(b.z, b.w);
  reinterpret_cast<uint4*>(out)[i] = r;
}

__device__ __forceinline__ void mkand_body(const uint8_t* __restrict__ m,
                                           uint16_t* __restrict__ out, int i) {
  uint2 v = reinterpret_cast<const uint2*>(m)[i];
  uint4 r;
  uint32_t lo = v.x, hi = v.y;
  uint16_t e[8];
#pragma unroll
  for (int j = 0; j < 4; j++) e[j]     = (uint16_t)(((lo >> (8 * j)) & 0xFF) - 1);
#pragma unroll
  for (int j = 0; j < 4; j++) e[4 + j] = (uint16_t)(((hi >> (8 * j)) & 0xFF) - 1);
  r.x = (uint32_t)e[0] | ((uint32_t)e[1] << 16);
  r.y = (uint32_t)e[2] | ((uint32_t)e[3] << 16);
  r.z = (uint32_t)e[4] | ((uint32_t)e[5] << 16);
  r.w = (uint32_t)e[6] | ((uint32_t)e[7] << 16);
  reinterpret_cast<uint4*>(out)[i] = r;
}

// ---------------------------------------------------------------------------
// prep: all f32->bf16 conversions (+ optional mask expansion) in ONE launch.
// ---------------------------------------------------------------------------
__global__ void __launch_bounds__(256)
prep(const float* __restrict__ hq, const float* __restrict__ hk,
     const float* __restrict__ hv, const float* __restrict__ Wq,
     const float* __restrict__ Wk, const float* __restrict__ Wv,
     const float* __restrict__ Wo,
     bf16_t* hq_b, bf16_t* hk_b, bf16_t* hv_b,
     bf16_t* Wq_b, bf16_t* Wk_b, bf16_t* Wv_b, bf16_t* Wo_b,
     const uint8_t* __restrict__ mask, uint16_t* __restrict__ mand) {
  const int bid = blockIdx.x;
  if (bid < 12288) {
    const int seg = bid >> 12;               // /4096
    const float* src = seg == 0 ? hq : seg == 1 ? hk : hv;
    bf16_t*      dst = seg == 0 ? hq_b : seg == 1 ? hk_b : hv_b;
    cvt8_body(src, dst, (bid & 4095) * 256 + (int)threadIdx.x);
  } else if (bid < 14336) {
    const int sb = bid - 12288;
    const int seg = sb >> 9;                 // /512
    const float* src = seg == 0 ? Wq : seg == 1 ? Wk : seg == 2 ? Wv : Wo;
    bf16_t*      dst = seg == 0 ? Wq_b : seg == 1 ? Wk_b : seg == 2 ? Wv_b : Wo_b;
    cvt8_body(src, dst, (sb & 511) * 256 + (int)threadIdx.x);
  } else {
    mkand_body(mask, mand, (bid - 14336) * 256 + (int)threadIdx.x);
  }
}

__global__ void __launch_bounds__(256)
mkand(const uint8_t* __restrict__ m, uint16_t* __restrict__ out) {
  mkand_body(m, out, blockIdx.x * 256 + (int)threadIdx.x);
}

// ---------------------------------------------------------------------------
// GEMM  C[M,N] = A[M,K] * Bw[N,K]^T, 128x128 tile, BK=32, double-buffered LDS
// (R10-proven: stage at top, __syncthreads at bottom). XCD-swizzled mapping.
// EPI 0: bf16 row-major, scaled by qscale (Q)
// EPI 1: V in attn-fragment order
// EPI 2: f32 + residual (out proj)
// EPI 3: K in attn-fragment order
// ---------------------------------------------------------------------------
#define BM 128
#define BN 128
#define BKT 32

template<int EPI>
__global__ void __launch_bounds__(256, 4)
gemm_bt(const bf16_t* __restrict__ A, const bf16_t* __restrict__ Bw,
        bf16_t* __restrict__ Cb, float* __restrict__ Cf,
        const float* __restrict__ resid, float qscale) {
  __shared__ bf16_t As[2][BM * BKT];
  __shared__ bf16_t Bs[2][BN * BKT];
  const int K = EMB, N = EMB;
  const int t    = threadIdx.x;
  const int lane = t & 63, w = t >> 6;
  const int wr = w >> 1, wc = w & 1;
  const int l15 = lane & 15, l4 = lane >> 4;

  const int lin = blockIdx.x + 8 * blockIdx.y;
  const int nl  = (lin & 7) * 64 + (lin >> 3);
  const int rowBase = (nl >> 3) * BM, colBase = (nl & 7) * BN;

  f32x4 acc[4][4];
#pragma unroll
  for (int i = 0; i < 4; i++)
#pragma unroll
    for (int j = 0; j < 4; j++) acc[i][j] = f32x4{0.f, 0.f, 0.f, 0.f};

  const int t16 = t * 16;

#pragma unroll
  for (int i = 0; i < 2; ++i) {
    int off  = i * 4096 + t16;
    int row  = off >> 6, colb = off & 63;
    gload_lds16((const char*)A  + (((size_t)(rowBase + row)) * K) * 2 + colb, (char*)As[0] + off);
    gload_lds16((const char*)Bw + (((size_t)(colBase + row)) * K) * 2 + colb, (char*)Bs[0] + off);
  }
  __syncthreads();

  int cur = 0;
  for (int k0 = 0; k0 < K; k0 += BKT) {
    if (k0 + BKT < K) {
      const int nb = cur ^ 1;
#pragma unroll
      for (int i = 0; i < 2; ++i) {
        int off  = i * 4096 + t16;
        int row  = off >> 6, colb = off & 63;
        gload_lds16((const char*)A  + (((size_t)(rowBase + row)) * K + k0 + BKT) * 2 + colb, (char*)As[nb] + off);
        gload_lds16((const char*)Bw + (((size_t)(colBase + row)) * K + k0 + BKT) * 2 + colb, (char*)Bs[nb] + off);
      }
    }
    {
      bf16x8 af[4], bfb[4];
#pragma unroll
      for (int mi = 0; mi < 4; mi++)
        af[mi] = *reinterpret_cast<const bf16x8*>(
            &As[cur][(wr * 64 + mi * 16 + l15) * BKT + l4 * 8]);
#pragma unroll
      for (int ni = 0; ni < 4; ni++)
        bfb[ni] = *reinterpret_cast<const bf16x8*>(
            &Bs[cur][(wc * 64 + ni * 16 + l15) * BKT + l4 * 8]);
      __builtin_amdgcn_s_setprio(1);
#pragma unroll
      for (int mi = 0; mi < 4; mi++)
#pragma unroll
        for (int ni = 0; ni < 4; ni++)
          acc[mi][ni] = __builtin_amdgcn_mfma_f32_16x16x32_bf16(
              af[mi], bfb[ni], acc[mi][ni], 0, 0, 0);
      __builtin_amdgcn_s_setprio(0);
    }
    __syncthreads();
    cur ^= 1;
  }

#pragma unroll
  for (int mi = 0; mi < 4; mi++) {
#pragma unroll
    for (int ni = 0; ni < 4; ni++) {
      const int m0 = rowBase + wr * 64 + mi * 16 + l4 * 4;
      const int n  = colBase + wc * 64 + ni * 16 + l15;
      if (EPI == 1) {
        const int bq = m0 >> 11, s0 = m0 & 2047, hh = n >> 6, d = n & 63;
        size_t local = (size_t)(s0 >> 6) * 4096 + ((s0 >> 4) & 3) * 1024 +
                       (d >> 5) * 512 + ((s0 >> 3) & 1) * 256 + (d & 31) * 8 + (s0 & 7);
        uint2 st;
        st.x = pkbf(acc[mi][ni][0], acc[mi][ni][1]);
        st.y = pkbf(acc[mi][ni][2], acc[mi][ni][3]);
        *reinterpret_cast<uint2*>(Cb + (size_t)(bq * 16 + hh) * 131072 + local) = st;
      } else {
#pragma unroll
        for (int r = 0; r < 4; r++) {
          int m = m0 + r;
          float v = acc[mi][ni][r];
          if (EPI == 0) {
            Cb[(size_t)m * N + n] = (bf16_t)(v * qscale);
          } else if (EPI == 3) {
            const int bq = m >> 11, s = m & 2047, hh = n >> 6, d = n & 63;
            size_t local = (size_t)(s >> 6) * 4096 + ((s >> 5) & 1) * 2048 +
                           (d >> 4) * 512 + ((d >> 3) & 1) * 256 + (s & 31) * 8 + (d & 7);
            Cb[(size_t)(bq * 16 + hh) * 131072 + local] = (bf16_t)v;
          } else {
            Cf[(size_t)m * N + n] = v + resid[(size_t)m * N + n];
          }
        }
      }
    }
  }
}

// ---------------------------------------------------------------------------
// Flash attention — R10 math with T15-style software pipelining: QK^T of tile
// t+1 (MFMA pipe, into n0/n1) overlaps softmax+PV of tile t (VALU pipe, on
// p0/p1). K triple-buffered (read distance 2), V double-buffered; stage
// discipline: every buffer overwrite is barrier-separated from its readers.
// 256 thr = 4 waves x 32 q-rows; 1024 blocks; __launch_bounds__(256,3)
// (VGPR cap ~168; two P-states ≈ 150 live). Spill canary: WRITE_SIZE.
// Fragment-ordered K/V: all LDS reads are base + frag*1024 + lane*16
// (conflict-free); staging is linear 8KB copies.
// ---------------------------------------------------------------------------
__global__ void __launch_bounds__(256, 3)
attn32(const bf16_t* __restrict__ Qb, const bf16_t* __restrict__ Kh,
       const bf16_t* __restrict__ Vt, const uint16_t* __restrict__ Mand,
       bf16_t* __restrict__ ctx) {
  __shared__ __align__(16) bf16_t Ks[3][64 * 64];   // 24 KB
  __shared__ __align__(16) bf16_t Vs[2][64 * 64];   // 16 KB

  const int t = threadIdx.x, lane = t & 63, wid = t >> 6;   // wid 0..3
  const int q = lane & 31, hi = lane >> 5;
  const int l16 = lane * 16;

  // XCD swizzle: 1024 blocks; blocks sharing (b,h) K/V land on the same XCD
  const int lin = blockIdx.x + 16 * (blockIdx.y + 16 * blockIdx.z);
  const int nl  = (lin & 7) * 128 + (lin >> 3);
  const int bx = nl & 15, h = (nl >> 4) & 15, b = nl >> 8;

  const int q0 = bx * 128 + wid * 32;
  const int qrow = b * SEQ + q0 + q;

  // fragment-ordered K/V: tile i occupies bytes [i*8192, i*8192+8192)
  const char* kg = (const char*)(Kh + ((size_t)(b * NB_HEAD + h)) * SEQ * DH);
  const char* vg = (const char*)(Vt + ((size_t)(b * NB_HEAD + h)) * SEQ * DH);

  const bf16_t* qp = Qb + (size_t)qrow * EMB + h * DH + hi * 8;
  bf16x8 qf[4];
#pragma unroll
  for (int d = 0; d < 4; d++) qf[d] = *reinterpret_cast<const bf16x8*>(qp + d * 16);

  f32x16 o0 = {0}, o1 = {0};
  float lrun = 0.f;
  const uint16_t* mbase = Mand + (size_t)qrow * SEQ;

  char* kA = (char*)Ks[0]; char* kB = (char*)Ks[1]; char* kC = (char*)Ks[2];
  char* vA = (char*)Vs[0]; char* vB = (char*)Vs[1];

  // prologue: K tiles 0,1 and V tile 0
  gload_lds16(kg + t * 16,        kA + t * 16);
  gload_lds16(kg + 4096 + t * 16, kA + 4096 + t * 16);
  gload_lds16(kg + 8192 + t * 16,        kB + t * 16);
  gload_lds16(kg + 8192 + 4096 + t * 16, kB + 4096 + t * 16);
  gload_lds16(vg + t * 16,        vA + t * 16);
  gload_lds16(vg + 4096 + t * 16, vA + 4096 + t * 16);
  __syncthreads();

  // QK^T of tile 0 from kA -> p0/p1
  f32x16 p0 = {0}, p1 = {0};
  __builtin_amdgcn_s_setprio(1);
#pragma unroll
  for (int dsl = 0; dsl < 4; dsl++) {
    bf16x8 kf0 = *reinterpret_cast<const bf16x8*>(kA + dsl * 1024 + l16);
    bf16x8 kf1 = *reinterpret_cast<const bf16x8*>(kA + 4096 + dsl * 1024 + l16);
    p0 = __builtin_amdgcn_mfma_f32_32x32x16_bf16(kf0, qf[dsl], p0, 0, 0, 0);
    p1 = __builtin_amdgcn_mfma_f32_32x32x16_bf16(kf1, qf[dsl], p1, 0, 0, 0);
  }
  __builtin_amdgcn_s_setprio(0);

#pragma unroll 1
  for (int tt = 0; tt < 32; ++tt) {
    // Barrier: all waves finished tile tt-1 reads; drains stages issued at
    // tt-1 (K tile tt+1 -> kB, V tile tt -> current buf). Overwrites below
    // target buffers whose readers are all before this barrier.
    __syncthreads();

    if (tt + 2 < 32) {
      const size_t o = (size_t)(tt + 2) * 8192;
      gload_lds16(kg + o + t * 16,        kC + t * 16);
      gload_lds16(kg + o + 4096 + t * 16, kC + 4096 + t * 16);
    }
    if (tt + 1 < 32) {
      const size_t o = (size_t)(tt + 1) * 8192;
      char* vdst = (tt & 1) ? vA : vB;     // tile tt+1 -> buf (tt+1)&1
      gload_lds16(vg + o + t * 16,        vdst + t * 16);
      gload_lds16(vg + o + 4096 + t * 16, vdst + 4096 + t * 16);
    }

    // ---- QK^T of tile tt+1 from kB -> n0/n1 (MFMA pipe; overlaps the
    //      softmax VALU below, which only touches p0/p1) ----
    f32x16 n0 = {0}, n1 = {0};
    if (tt + 1 < 32) {
      __builtin_amdgcn_s_setprio(1);
#pragma unroll
      for (int dsl = 0; dsl < 4; dsl++) {
        bf16x8 kf0 = *reinterpret_cast<const bf16x8*>(kB + dsl * 1024 + l16);
        bf16x8 kf1 = *reinterpret_cast<const bf16x8*>(kB + 4096 + dsl * 1024 + l16);
        n0 = __builtin_amdgcn_mfma_f32_32x32x16_bf16(kf0, qf[dsl], n0, 0, 0, 0);
        n1 = __builtin_amdgcn_mfma_f32_32x32x16_bf16(kf1, qf[dsl], n1, 0, 0, 0);
      }
      __builtin_amdgcn_s_setprio(0);
    }

    // ---- mask loads (short live range) ----
    uint4 mv[4];
#pragma unroll
    for (int ks = 0; ks < 4; ks++)
      mv[ks] = *reinterpret_cast<const uint4*>(mbase + tt * 64 + 16 * ks + 8 * hi);

    // ---- softmax of tile tt (p0/p1): exp2, unmasked denominator ----
    float ps = 0.f;
#pragma unroll
    for (int i = 0; i < 16; i++) { p0[i] = __builtin_amdgcn_exp2f(p0[i]); ps += p0[i]; }
#pragma unroll
    for (int i = 0; i < 16; i++) { p1[i] = __builtin_amdgcn_exp2f(p1[i]); ps += p1[i]; }
    ps += __shfl_xor(ps, 32);
    lrun += ps;

    // ---- build PA fragments (permlane32_swap), mask, PV from V[tt&1] ----
    const char* vls = (tt & 1) ? vB : vA;
#pragma unroll
    for (int ks = 0; ks < 4; ks++) {
      const int s8 = (ks & 1) * 8;
      float e0, e1, e2, e3, e4, e5, e6, e7;
      if (ks < 2) {
        e0 = p0[s8+0]; e1 = p0[s8+1]; e2 = p0[s8+2]; e3 = p0[s8+3];
        e4 = p0[s8+4]; e5 = p0[s8+5]; e6 = p0[s8+6]; e7 = p0[s8+7];
      } else {
        e0 = p1[s8+0]; e1 = p1[s8+1]; e2 = p1[s8+2]; e3 = p1[s8+3];
        e4 = p1[s8+4]; e5 = p1[s8+5]; e6 = p1[s8+6]; e7 = p1[s8+7];
      }
      uint32_t a0 = pkbf(e0, e1), a1 = pkbf(e2, e3);
      uint32_t a2 = pkbf(e4, e5), a3 = pkbf(e6, e7);
      uint2v s02 = __builtin_amdgcn_permlane32_swap(a0, a2, false, false);
      uint2v s13 = __builtin_amdgcn_permlane32_swap(a1, a3, false, false);
      uint4 fr;
      fr.x = s02[0]; fr.y = s13[0]; fr.z = s02[1]; fr.w = s13[1];
      fr.x &= mv[ks].x; fr.y &= mv[ks].y; fr.z &= mv[ks].z; fr.w &= mv[ks].w;
      bf16x8 pa = __builtin_bit_cast(bf16x8, fr);
      bf16x8 vf0 = *reinterpret_cast<const bf16x8*>(vls + ks * 2048 + l16);
      bf16x8 vf1 = *reinterpret_cast<const bf16x8*>(vls + ks * 2048 + 1024 + l16);
      __builtin_amdgcn_s_setprio(1);
      o0 = __builtin_amdgcn_mfma_f32_32x32x16_bf16(vf0, pa, o0, 0, 0, 0);
      o1 = __builtin_amdgcn_mfma_f32_32x32x16_bf16(vf1, pa, o1, 0, 0, 0);
      __builtin_amdgcn_s_setprio(0);
    }

    // ---- rotate P-state and K buffers ----
    p0 = n0; p1 = n1;
    char* ktmp = kA; kA = kB; kB = kC; kC = ktmp;
  }

  // ---- epilogue ----
  float inv = 1.0f / lrun;
  bf16_t* cp = ctx + (size_t)qrow * EMB + h * DH;
#pragma unroll
  for (int g = 0; g < 4; g++) {
    uint2 st;
    st.x = pkbf(o0[4*g+0] * inv, o0[4*g+1] * inv);
    st.y = pkbf(o0[4*g+2] * inv, o0[4*g+3] * inv);
    *reinterpret_cast<uint2*>(cp + 8 * g + 4 * hi) = st;
    st.x = pkbf(o1[4*g+0] * inv, o1[4*g+1] * inv);
    st.y = pkbf(o1[4*g+2] * inv, o1[4*g+3] * inv);
    *reinterpret_cast<uint2*>(cp + 32 + 8 * g + 4 * hi) = st;
  }
}

// ---------------------------------------------------------------------------
// launcher
// ---------------------------------------------------------------------------
extern "C" void kernel_launch(void* const* d_in, const int* in_sizes, int n_in,
                              void* d_out, int out_size, void* d_ws, size_t ws_size,
                              hipStream_t stream) {
  const float*   hq   = (const float*)d_in[0];
  const float*   hk   = (const float*)d_in[1];
  const float*   hv   = (const float*)d_in[2];
  const uint8_t* mask = (const uint8_t*)d_in[3];
  const float*   Wq   = (const float*)d_in[4];
  const float*   Wk   = (const float*)d_in[5];
  const float*   Wv   = (const float*)d_in[6];
  const float*   Wo   = (const float*)d_in[7];
  float* out = (float*)d_out;

  char* ws = (char*)d_ws;
  const size_t SZ_H = (size_t)NTOK * EMB * 2;        // 16 MiB
  const size_t SZ_W = (size_t)EMB * EMB * 2;         // 2 MiB
  bf16_t* hq_b = (bf16_t*)(ws + 0 * SZ_H);
  bf16_t* hk_b = (bf16_t*)(ws + 1 * SZ_H);
  bf16_t* hv_b = (bf16_t*)(ws + 2 * SZ_H);
  bf16_t* Qb   = (bf16_t*)(ws + 3 * SZ_H);
  bf16_t* Kf   = (bf16_t*)(ws + 4 * SZ_H);
  bf16_t* Vf   = (bf16_t*)(ws + 5 * SZ_H);
  bf16_t* ctx  = (bf16_t*)(ws + 6 * SZ_H);
  bf16_t* Wq_b = (bf16_t*)(ws + 7 * SZ_H + 0 * SZ_W);
  bf16_t* Wk_b = (bf16_t*)(ws + 7 * SZ_H + 1 * SZ_W);
  bf16_t* Wv_b = (bf16_t*)(ws + 7 * SZ_H + 2 * SZ_W);
  bf16_t* Wo_b = (bf16_t*)(ws + 7 * SZ_H + 3 * SZ_W);

  const size_t MAND_OFF = 7 * SZ_H + 4 * SZ_W;                 // 120 MiB
  const size_t MAND_SZ  = (size_t)BATCH * SEQ * SEQ * 2;       // 32 MiB
  const bool bigws = ws_size >= MAND_OFF + MAND_SZ;
  // fallback: Mand aliases hq_b/hk_b/hv_b (dead after the QKV gemms)
  uint16_t* Mand = bigws ? (uint16_t*)(ws + MAND_OFF) : (uint16_t*)ws;

  prep<<<bigws ? 22528 : 14336, 256, 0, stream>>>(
      hq, hk, hv, Wq, Wk, Wv, Wo,
      hq_b, hk_b, hv_b, Wq_b, Wk_b, Wv_b, Wo_b, mask, Mand);

  dim3 ggrid(EMB / BN, NTOK / BM);  // (8, 64)
  gemm_bt<0><<<ggrid, 256, 0, stream>>>(hq_b, Wq_b, Qb, nullptr, nullptr, QSCALE);
  gemm_bt<3><<<ggrid, 256, 0, stream>>>(hk_b, Wk_b, Kf, nullptr, nullptr, 1.0f);
  gemm_bt<1><<<ggrid, 256, 0, stream>>>(hv_b, Wv_b, Vf, nullptr, nullptr, 1.0f);

  if (!bigws) mkand<<<8192, 256, 0, stream>>>(mask, Mand);

  attn32<<<dim3(SEQ / 128, NB_HEAD, BATCH), 256, 0, stream>>>(Qb, Kf, Vf, Mand, ctx);

  gemm_bt<2><<<ggrid, 256, 0, stream>>>(ctx, Wo_b, nullptr, out, hq, 1.0f);
}

// Round 15
// 229.706 us; speedup vs baseline: 1.1327x; 1.1327x over previous
//
#include <hip/hip_runtime.h>
#include <hip/hip_bf16.h>
#include <stdint.h>

typedef __bf16 bf16_t;
typedef bf16_t bf16x2 __attribute__((ext_vector_type(2)));
typedef bf16_t bf16x8 __attribute__((ext_vector_type(8)));
typedef float  f32x4  __attribute__((ext_vector_type(4)));
typedef float  f32x16 __attribute__((ext_vector_type(16)));
typedef unsigned uint2v __attribute__((ext_vector_type(2)));

#define NB_HEAD 16
#define DH      64
#define EMB     1024
#define BATCH   4
#define SEQ     2048
#define NTOK    (BATCH*SEQ)   // 8192

// scale * log2(e): folded into Q at projection time
#define QSCALE 0.1803368801111204f

// ---------------------------------------------------------------------------
// helpers
// ---------------------------------------------------------------------------
__device__ __forceinline__ void gload_lds16(const void* g, void* l) {
  __builtin_amdgcn_global_load_lds(
      (const __attribute__((address_space(1))) void*)g,
      (__attribute__((address_space(3))) void*)l, 16, 0, 0);
}

__device__ __forceinline__ uint32_t pkbf(float a, float b) {
  bf16x2 v = { (bf16_t)a, (bf16_t)b };     // fusable to v_cvt_pk_bf16_f32
  return __builtin_bit_cast(uint32_t, v);
}

__device__ __forceinline__ void cvt8_body(const float* __restrict__ in,
                                          bf16_t* __restrict__ out, int i) {
  const float4* p = reinterpret_cast<const float4*>(in) + (size_t)i * 2;
  float4 a = p[0], b = p[1];
  uint4 r;
  r.x = pkbf(a.x, a.y); r.y = pkbf(a.z, a.w);
  r.z = pkbf(b.x, b.y); r.w = pkbf(b.z, b.w);
  reinterpret_cast<uint4*>(out)[i] = r;
}

__device__ __forceinline__ void mkand_body(const uint8_t* __restrict__ m,
                                           uint16_t* __restrict__ out, int i) {
  uint2 v = reinterpret_cast<const uint2*>(m)[i];
  uint4 r;
  uint32_t lo = v.x, hi = v.y;
  uint16_t e[8];
#pragma unroll
  for (int j = 0; j < 4; j++) e[j]     = (uint16_t)(((lo >> (8 * j)) & 0xFF) - 1);
#pragma unroll
  for (int j = 0; j < 4; j++) e[4 + j] = (uint16_t)(((hi >> (8 * j)) & 0xFF) - 1);
  r.x = (uint32_t)e[0] | ((uint32_t)e[1] << 16);
  r.y = (uint32_t)e[2] | ((uint32_t)e[3] << 16);
  r.z = (uint32_t)e[4] | ((uint32_t)e[5] << 16);
  r.w = (uint32_t)e[6] | ((uint32_t)e[7] << 16);
  reinterpret_cast<uint4*>(out)[i] = r;
}

// ---------------------------------------------------------------------------
// prep: all f32->bf16 conversions (+ optional mask expansion) in ONE launch.
// ---------------------------------------------------------------------------
__global__ void __launch_bounds__(256)
prep(const float* __restrict__ hq, const float* __restrict__ hk,
     const float* __restrict__ hv, const float* __restrict__ Wq,
     const float* __restrict__ Wk, const float* __restrict__ Wv,
     const float* __restrict__ Wo,
     bf16_t* hq_b, bf16_t* hk_b, bf16_t* hv_b,
     bf16_t* Wq_b, bf16_t* Wk_b, bf16_t* Wv_b, bf16_t* Wo_b,
     const uint8_t* __restrict__ mask, uint16_t* __restrict__ mand) {
  const int bid = blockIdx.x;
  if (bid < 12288) {
    const int seg = bid >> 12;               // /4096
    const float* src = seg == 0 ? hq : seg == 1 ? hk : hv;
    bf16_t*      dst = seg == 0 ? hq_b : seg == 1 ? hk_b : hv_b;
    cvt8_body(src, dst, (bid & 4095) * 256 + (int)threadIdx.x);
  } else if (bid < 14336) {
    const int sb = bid - 12288;
    const int seg = sb >> 9;                 // /512
    const float* src = seg == 0 ? Wq : seg == 1 ? Wk : seg == 2 ? Wv : Wo;
    bf16_t*      dst = seg == 0 ? Wq_b : seg == 1 ? Wk_b : seg == 2 ? Wv_b : Wo_b;
    cvt8_body(src, dst, (sb & 511) * 256 + (int)threadIdx.x);
  } else {
    mkand_body(mask, mand, (bid - 14336) * 256 + (int)threadIdx.x);
  }
}

__global__ void __launch_bounds__(256)
mkand(const uint8_t* __restrict__ m, uint16_t* __restrict__ out) {
  mkand_body(m, out, blockIdx.x * 256 + (int)threadIdx.x);
}

#define BM 128
#define BN 128
#define BKT 32

// ---------------------------------------------------------------------------
// Fused QKV GEMM: ONE launch, grid (8,64,3) = 1536 blocks (4+ blocks/CU fill
// vs 512-block single GEMMs at 2/CU). Inner loop is the R10-proven gemm_bt
// body UNCHANGED — only pointer selection and the epilogue switch on z.
// z=0: Q bf16 row-major x QSCALE; z=1: K attn-fragment; z=2: V attn-fragment.
// ---------------------------------------------------------------------------
__global__ void __launch_bounds__(256, 4)
gemm_qkv3(const bf16_t* __restrict__ hq_b, const bf16_t* __restrict__ hk_b,
          const bf16_t* __restrict__ hv_b,
          const bf16_t* __restrict__ Wq_b, const bf16_t* __restrict__ Wk_b,
          const bf16_t* __restrict__ Wv_b,
          bf16_t* __restrict__ Qb, bf16_t* __restrict__ Kf,
          bf16_t* __restrict__ Vf) {
  __shared__ bf16_t As[2][BM * BKT];
  __shared__ bf16_t Bs[2][BN * BKT];
  const int K = EMB, N = EMB;
  const int z = blockIdx.z;
  const bf16_t* A  = z == 0 ? hq_b : z == 1 ? hk_b : hv_b;
  const bf16_t* Bw = z == 0 ? Wq_b : z == 1 ? Wk_b : Wv_b;

  const int t    = threadIdx.x;
  const int lane = t & 63, w = t >> 6;
  const int wr = w >> 1, wc = w & 1;
  const int l15 = lane & 15, l4 = lane >> 4;

  // XCD swizzle within each z-slice
  const int lin = blockIdx.x + 8 * blockIdx.y;
  const int nl  = (lin & 7) * 64 + (lin >> 3);
  const int rowBase = (nl >> 3) * BM, colBase = (nl & 7) * BN;

  f32x4 acc[4][4];
#pragma unroll
  for (int i = 0; i < 4; i++)
#pragma unroll
    for (int j = 0; j < 4; j++) acc[i][j] = f32x4{0.f, 0.f, 0.f, 0.f};

  const int t16 = t * 16;

#pragma unroll
  for (int i = 0; i < 2; ++i) {
    int off  = i * 4096 + t16;
    int row  = off >> 6, colb = off & 63;
    gload_lds16((const char*)A  + (((size_t)(rowBase + row)) * K) * 2 + colb, (char*)As[0] + off);
    gload_lds16((const char*)Bw + (((size_t)(colBase + row)) * K) * 2 + colb, (char*)Bs[0] + off);
  }
  __syncthreads();

  int cur = 0;
  for (int k0 = 0; k0 < K; k0 += BKT) {
    if (k0 + BKT < K) {
      const int nb = cur ^ 1;
#pragma unroll
      for (int i = 0; i < 2; ++i) {
        int off  = i * 4096 + t16;
        int row  = off >> 6, colb = off & 63;
        gload_lds16((const char*)A  + (((size_t)(rowBase + row)) * K + k0 + BKT) * 2 + colb, (char*)As[nb] + off);
        gload_lds16((const char*)Bw + (((size_t)(colBase + row)) * K + k0 + BKT) * 2 + colb, (char*)Bs[nb] + off);
      }
    }
    {
      bf16x8 af[4], bfb[4];
#pragma unroll
      for (int mi = 0; mi < 4; mi++)
        af[mi] = *reinterpret_cast<const bf16x8*>(
            &As[cur][(wr * 64 + mi * 16 + l15) * BKT + l4 * 8]);
#pragma unroll
      for (int ni = 0; ni < 4; ni++)
        bfb[ni] = *reinterpret_cast<const bf16x8*>(
            &Bs[cur][(wc * 64 + ni * 16 + l15) * BKT + l4 * 8]);
      __builtin_amdgcn_s_setprio(1);
#pragma unroll
      for (int mi = 0; mi < 4; mi++)
#pragma unroll
        for (int ni = 0; ni < 4; ni++)
          acc[mi][ni] = __builtin_amdgcn_mfma_f32_16x16x32_bf16(
              af[mi], bfb[ni], acc[mi][ni], 0, 0, 0);
      __builtin_amdgcn_s_setprio(0);
    }
    __syncthreads();
    cur ^= 1;
  }

#pragma unroll
  for (int mi = 0; mi < 4; mi++) {
#pragma unroll
    for (int ni = 0; ni < 4; ni++) {
      const int m0 = rowBase + wr * 64 + mi * 16 + l4 * 4;
      const int n  = colBase + wc * 64 + ni * 16 + l15;
      if (z == 0) {
#pragma unroll
        for (int r = 0; r < 4; r++)
          Qb[(size_t)(m0 + r) * EMB + n] = (bf16_t)(acc[mi][ni][r] * QSCALE);
      } else if (z == 1) {
        // K fragment layout
#pragma unroll
        for (int r = 0; r < 4; r++) {
          int m = m0 + r;
          const int bq = m >> 11, s = m & 2047, hh = n >> 6, d = n & 63;
          size_t local = (size_t)(s >> 6) * 4096 + ((s >> 5) & 1) * 2048 +
                         (d >> 4) * 512 + ((d >> 3) & 1) * 256 + (s & 31) * 8 + (d & 7);
          Kf[(size_t)(bq * 16 + hh) * 131072 + local] = (bf16_t)acc[mi][ni][r];
        }
      } else {
        // V fragment layout: s0..s0+3 consecutive -> one 8B store
        const int bq = m0 >> 11, s0 = m0 & 2047, hh = n >> 6, d = n & 63;
        size_t local = (size_t)(s0 >> 6) * 4096 + ((s0 >> 4) & 3) * 1024 +
                       (d >> 5) * 512 + ((s0 >> 3) & 1) * 256 + (d & 31) * 8 + (s0 & 7);
        uint2 st;
        st.x = pkbf(acc[mi][ni][0], acc[mi][ni][1]);
        st.y = pkbf(acc[mi][ni][2], acc[mi][ni][3]);
        *reinterpret_cast<uint2*>(Vf + (size_t)(bq * 16 + hh) * 131072 + local) = st;
      }
    }
  }
}

// ---------------------------------------------------------------------------
// Output-projection GEMM (R10 gemm_bt<2> verbatim): f32 C + residual.
// ---------------------------------------------------------------------------
__global__ void __launch_bounds__(256, 4)
gemm_out(const bf16_t* __restrict__ A, const bf16_t* __restrict__ Bw,
         float* __restrict__ Cf, const float* __restrict__ resid) {
  __shared__ bf16_t As[2][BM * BKT];
  __shared__ bf16_t Bs[2][BN * BKT];
  const int K = EMB, N = EMB;
  const int t    = threadIdx.x;
  const int lane = t & 63, w = t >> 6;
  const int wr = w >> 1, wc = w & 1;
  const int l15 = lane & 15, l4 = lane >> 4;

  const int lin = blockIdx.x + 8 * blockIdx.y;
  const int nl  = (lin & 7) * 64 + (lin >> 3);
  const int rowBase = (nl >> 3) * BM, colBase = (nl & 7) * BN;

  f32x4 acc[4][4];
#pragma unroll
  for (int i = 0; i < 4; i++)
#pragma unroll
    for (int j = 0; j < 4; j++) acc[i][j] = f32x4{0.f, 0.f, 0.f, 0.f};

  const int t16 = t * 16;

#pragma unroll
  for (int i = 0; i < 2; ++i) {
    int off  = i * 4096 + t16;
    int row  = off >> 6, colb = off & 63;
    gload_lds16((const char*)A  + (((size_t)(rowBase + row)) * K) * 2 + colb, (char*)As[0] + off);
    gload_lds16((const char*)Bw + (((size_t)(colBase + row)) * K) * 2 + colb, (char*)Bs[0] + off);
  }
  __syncthreads();

  int cur = 0;
  for (int k0 = 0; k0 < K; k0 += BKT) {
    if (k0 + BKT < K) {
      const int nb = cur ^ 1;
#pragma unroll
      for (int i = 0; i < 2; ++i) {
        int off  = i * 4096 + t16;
        int row  = off >> 6, colb = off & 63;
        gload_lds16((const char*)A  + (((size_t)(rowBase + row)) * K + k0 + BKT) * 2 + colb, (char*)As[nb] + off);
        gload_lds16((const char*)Bw + (((size_t)(colBase + row)) * K + k0 + BKT) * 2 + colb, (char*)Bs[nb] + off);
      }
    }
    {
      bf16x8 af[4], bfb[4];
#pragma unroll
      for (int mi = 0; mi < 4; mi++)
        af[mi] = *reinterpret_cast<const bf16x8*>(
            &As[cur][(wr * 64 + mi * 16 + l15) * BKT + l4 * 8]);
#pragma unroll
      for (int ni = 0; ni < 4; ni++)
        bfb[ni] = *reinterpret_cast<const bf16x8*>(
            &Bs[cur][(wc * 64 + ni * 16 + l15) * BKT + l4 * 8]);
      __builtin_amdgcn_s_setprio(1);
#pragma unroll
      for (int mi = 0; mi < 4; mi++)
#pragma unroll
        for (int ni = 0; ni < 4; ni++)
          acc[mi][ni] = __builtin_amdgcn_mfma_f32_16x16x32_bf16(
              af[mi], bfb[ni], acc[mi][ni], 0, 0, 0);
      __builtin_amdgcn_s_setprio(0);
    }
    __syncthreads();
    cur ^= 1;
  }

#pragma unroll
  for (int mi = 0; mi < 4; mi++) {
#pragma unroll
    for (int ni = 0; ni < 4; ni++) {
      const int m0 = rowBase + wr * 64 + mi * 16 + l4 * 4;
      const int n  = colBase + wc * 64 + ni * 16 + l15;
#pragma unroll
      for (int r = 0; r < 4; r++) {
        int m = m0 + r;
        Cf[(size_t)m * N + n] = acc[mi][ni][r] + resid[(size_t)m * N + n];
      }
    }
  }
}

// ---------------------------------------------------------------------------
// Flash attention — EXACT R10 kernel (106.0 us: VGPR 56, no scratch, 0 bank
// conflicts). 512 thr = 8 waves x 32 q-rows; KVBLK=64; fragment-ordered K/V
// (LDS reads = base + frag*1024 + lane*16; staging = linear 8KB copies).
// Swapped-operand 32x32x16, POST-softmax masking, no online max (Q
// pre-scaled; P = exp2(acc)), VALU ps denominator.
// *** FROZEN. Six structural variants tried: KVB=128/mask-hoist (R5-R8:
// *** scratch spills), occupancy/phase-diversity (R11: null), no-LDS (R12:
// *** latency-bound), T15 pipeline (R14: -16%). Do not restructure.
// ---------------------------------------------------------------------------
__global__ void __launch_bounds__(512, 2)
attn32(const bf16_t* __restrict__ Qb, const bf16_t* __restrict__ Kh,
       const bf16_t* __restrict__ Vt, const uint16_t* __restrict__ Mand,
       bf16_t* __restrict__ ctx) {
  __shared__ __align__(16) bf16_t Ks[2][64 * 64];
  __shared__ __align__(16) bf16_t Vs[2][64 * 64];

  const int t = threadIdx.x, lane = t & 63, wid = t >> 6;
  const int q = lane & 31, hi = lane >> 5;
  const int l16 = lane * 16;

  // XCD swizzle: 512 blocks; mask/K/V sharers land on the same XCD
  const int lin = blockIdx.x + 8 * (blockIdx.y + 16 * blockIdx.z);
  const int nl  = (lin & 7) * 64 + (lin >> 3);
  const int bx = nl & 7, h = (nl >> 3) & 15, b = nl >> 7;

  const int q0 = bx * 256 + wid * 32;
  const int qrow = b * SEQ + q0 + q;

  const char* kg = (const char*)(Kh + ((size_t)(b * NB_HEAD + h)) * SEQ * DH);
  const char* vg = (const char*)(Vt + ((size_t)(b * NB_HEAD + h)) * SEQ * DH);

  const bf16_t* qp = Qb + (size_t)qrow * EMB + h * DH + hi * 8;
  bf16x8 qf[4];
#pragma unroll
  for (int d = 0; d < 4; d++) qf[d] = *reinterpret_cast<const bf16x8*>(qp + d * 16);

  f32x16 o0 = {0}, o1 = {0};
  float lrun = 0.f;
  const uint16_t* mbase = Mand + (size_t)qrow * SEQ;

  // prologue: stage tile 0 into buf 0 (linear 8KB copies)
  gload_lds16(kg + t * 16, (char*)Ks[0] + t * 16);
  gload_lds16(vg + t * 16, (char*)Vs[0] + t * 16);
  __syncthreads();

  int cur = 0;
  for (int kb = 0; kb < SEQ; kb += 64) {
    if (kb + 64 < SEQ) {
      const int nb = cur ^ 1;
      gload_lds16(kg + (size_t)(kb + 64) * 128 + t * 16, (char*)Ks[nb] + t * 16);
      gload_lds16(vg + (size_t)(kb + 64) * 128 + t * 16, (char*)Vs[nb] + t * 16);
    }

    const char* kls = (const char*)Ks[cur];
    f32x16 p0 = {0}, p1 = {0};
    __builtin_amdgcn_s_setprio(1);
#pragma unroll
    for (int dsl = 0; dsl < 4; dsl++) {
      bf16x8 kf0 = *reinterpret_cast<const bf16x8*>(kls + dsl * 1024 + l16);
      bf16x8 kf1 = *reinterpret_cast<const bf16x8*>(kls + 4096 + dsl * 1024 + l16);
      p0 = __builtin_amdgcn_mfma_f32_32x32x16_bf16(kf0, qf[dsl], p0, 0, 0, 0);
      p1 = __builtin_amdgcn_mfma_f32_32x32x16_bf16(kf1, qf[dsl], p1, 0, 0, 0);
    }
    __builtin_amdgcn_s_setprio(0);

    uint4 mv[4];
#pragma unroll
    for (int ks = 0; ks < 4; ks++)
      mv[ks] = *reinterpret_cast<const uint4*>(mbase + kb + 16 * ks + 8 * hi);

    float ps = 0.f;
#pragma unroll
    for (int i = 0; i < 16; i++) { p0[i] = __builtin_amdgcn_exp2f(p0[i]); ps += p0[i]; }
#pragma unroll
    for (int i = 0; i < 16; i++) { p1[i] = __builtin_amdgcn_exp2f(p1[i]); ps += p1[i]; }
    ps += __shfl_xor(ps, 32);
    lrun += ps;

    const char* vls = (const char*)Vs[cur];
#pragma unroll
    for (int ks = 0; ks < 4; ks++) {
      const int s8 = (ks & 1) * 8;
      float e0, e1, e2, e3, e4, e5, e6, e7;
      if (ks < 2) {
        e0 = p0[s8+0]; e1 = p0[s8+1]; e2 = p0[s8+2]; e3 = p0[s8+3];
        e4 = p0[s8+4]; e5 = p0[s8+5]; e6 = p0[s8+6]; e7 = p0[s8+7];
      } else {
        e0 = p1[s8+0]; e1 = p1[s8+1]; e2 = p1[s8+2]; e3 = p1[s8+3];
        e4 = p1[s8+4]; e5 = p1[s8+5]; e6 = p1[s8+6]; e7 = p1[s8+7];
      }
      uint32_t a0 = pkbf(e0, e1), a1 = pkbf(e2, e3);
      uint32_t a2 = pkbf(e4, e5), a3 = pkbf(e6, e7);
      uint2v s02 = __builtin_amdgcn_permlane32_swap(a0, a2, false, false);
      uint2v s13 = __builtin_amdgcn_permlane32_swap(a1, a3, false, false);
      uint4 fr;
      fr.x = s02[0]; fr.y = s13[0]; fr.z = s02[1]; fr.w = s13[1];
      fr.x &= mv[ks].x; fr.y &= mv[ks].y; fr.z &= mv[ks].z; fr.w &= mv[ks].w;
      bf16x8 pa = __builtin_bit_cast(bf16x8, fr);
      bf16x8 vf0 = *reinterpret_cast<const bf16x8*>(vls + ks * 2048 + l16);
      bf16x8 vf1 = *reinterpret_cast<const bf16x8*>(vls + ks * 2048 + 1024 + l16);
      __builtin_amdgcn_s_setprio(1);
      o0 = __builtin_amdgcn_mfma_f32_32x32x16_bf16(vf0, pa, o0, 0, 0, 0);
      o1 = __builtin_amdgcn_mfma_f32_32x32x16_bf16(vf1, pa, o1, 0, 0, 0);
      __builtin_amdgcn_s_setprio(0);
    }

    __syncthreads();
    cur ^= 1;
  }

  float inv = 1.0f / lrun;
  bf16_t* cp = ctx + (size_t)qrow * EMB + h * DH;
#pragma unroll
  for (int g = 0; g < 4; g++) {
    uint2 st;
    st.x = pkbf(o0[4*g+0] * inv, o0[4*g+1] * inv);
    st.y = pkbf(o0[4*g+2] * inv, o0[4*g+3] * inv);
    *reinterpret_cast<uint2*>(cp + 8 * g + 4 * hi) = st;
    st.x = pkbf(o1[4*g+0] * inv, o1[4*g+1] * inv);
    st.y = pkbf(o1[4*g+2] * inv, o1[4*g+3] * inv);
    *reinterpret_cast<uint2*>(cp + 32 + 8 * g + 4 * hi) = st;
  }
}

// ---------------------------------------------------------------------------
// launcher
// ---------------------------------------------------------------------------
extern "C" void kernel_launch(void* const* d_in, const int* in_sizes, int n_in,
                              void* d_out, int out_size, void* d_ws, size_t ws_size,
                              hipStream_t stream) {
  const float*   hq   = (const float*)d_in[0];
  const float*   hk   = (const float*)d_in[1];
  const float*   hv   = (const float*)d_in[2];
  const uint8_t* mask = (const uint8_t*)d_in[3];
  const float*   Wq   = (const float*)d_in[4];
  const float*   Wk   = (const float*)d_in[5];
  const float*   Wv   = (const float*)d_in[6];
  const float*   Wo   = (const float*)d_in[7];
  float* out = (float*)d_out;

  char* ws = (char*)d_ws;
  const size_t SZ_H = (size_t)NTOK * EMB * 2;        // 16 MiB
  const size_t SZ_W = (size_t)EMB * EMB * 2;         // 2 MiB
  bf16_t* hq_b = (bf16_t*)(ws + 0 * SZ_H);
  bf16_t* hk_b = (bf16_t*)(ws + 1 * SZ_H);
  bf16_t* hv_b = (bf16_t*)(ws + 2 * SZ_H);
  bf16_t* Qb   = (bf16_t*)(ws + 3 * SZ_H);
  bf16_t* Kf   = (bf16_t*)(ws + 4 * SZ_H);
  bf16_t* Vf   = (bf16_t*)(ws + 5 * SZ_H);
  bf16_t* ctx  = (bf16_t*)(ws + 6 * SZ_H);
  bf16_t* Wq_b = (bf16_t*)(ws + 7 * SZ_H + 0 * SZ_W);
  bf16_t* Wk_b = (bf16_t*)(ws + 7 * SZ_H + 1 * SZ_W);
  bf16_t* Wv_b = (bf16_t*)(ws + 7 * SZ_H + 2 * SZ_W);
  bf16_t* Wo_b = (bf16_t*)(ws + 7 * SZ_H + 3 * SZ_W);

  const size_t MAND_OFF = 7 * SZ_H + 4 * SZ_W;                 // 120 MiB
  const size_t MAND_SZ  = (size_t)BATCH * SEQ * SEQ * 2;       // 32 MiB
  const bool bigws = ws_size >= MAND_OFF + MAND_SZ;
  // fallback: Mand aliases hq_b/hk_b/hv_b (dead after the QKV gemms)
  uint16_t* Mand = bigws ? (uint16_t*)(ws + MAND_OFF) : (uint16_t*)ws;

  prep<<<bigws ? 22528 : 14336, 256, 0, stream>>>(
      hq, hk, hv, Wq, Wk, Wv, Wo,
      hq_b, hk_b, hv_b, Wq_b, Wk_b, Wv_b, Wo_b, mask, Mand);

  // fused QKV: 1536 blocks -> 4+ blocks/CU (was 3 launches x 512 blocks)
  gemm_qkv3<<<dim3(8, 64, 3), 256, 0, stream>>>(hq_b, hk_b, hv_b,
                                                Wq_b, Wk_b, Wv_b, Qb, Kf, Vf);

  if (!bigws) mkand<<<8192, 256, 0, stream>>>(mask, Mand);

  attn32<<<dim3(SEQ / 256, NB_HEAD, BATCH), 512, 0, stream>>>(Qb, Kf, Vf, Mand, ctx);

  gemm_out<<<dim3(8, 64), 256, 0, stream>>>(ctx, Wo_b, out, hq);
}